// Round 7
// baseline (351.448 us; speedup 1.0000x reference)
//
#include <hip/hip_runtime.h>
#include <math.h>

// Problem constants
#define NB   8
#define NPIX 4096          // H*W
#define MROW 32768         // B*H*W
#define CV_  256
#define TT   77
#define CT_  512
#define NH_  8
#define DH_  32
#define BT_  616           // B*T

typedef __bf16 bf16x8 __attribute__((ext_vector_type(8)));
typedef float  f32x4  __attribute__((ext_vector_type(4)));

__device__ __forceinline__ float bf2f(unsigned short u) {
  return __uint_as_float(((unsigned)u) << 16);
}
__device__ __forceinline__ unsigned short f2b(float f) {
  unsigned u = __float_as_uint(f);
  return (unsigned short)((u + 0x7FFFu + ((u >> 16) & 1u)) >> 16);
}
__device__ __forceinline__ unsigned pack2(float lo, float hi) {
  return ((unsigned)f2b(hi) << 16) | (unsigned)f2b(lo);
}
__device__ __forceinline__ void async_copy16(const unsigned short* g,
                                             unsigned short* l) {
  __builtin_amdgcn_global_load_lds(
      (const __attribute__((address_space(1))) void*)g,
      (__attribute__((address_space(3))) void*)l, 16, 0, 0);
}

// -- prep: LN1 (0..8191) + weight convT + kv bias (..11777) + pad (..11931) --
__global__ __launch_bounds__(256) void prep_kernel(
    const float* __restrict__ visual, const float* __restrict__ g1,
    const float* __restrict__ b1, unsigned short* __restrict__ xbuf,
    const float* __restrict__ s0, const float* __restrict__ s1,
    const float* __restrict__ s2, const float* __restrict__ s3,
    const float* __restrict__ s4, const float* __restrict__ s5,
    unsigned short* __restrict__ d0, unsigned short* __restrict__ d1,
    unsigned short* __restrict__ d2, unsigned short* __restrict__ d3,
    unsigned short* __restrict__ d4, unsigned short* __restrict__ d5,
    const float* __restrict__ bk, const float* __restrict__ bv,
    float* __restrict__ bkv, const float* __restrict__ text,
    float* __restrict__ padb) {
  int bx = blockIdx.x;
  int wave = threadIdx.x >> 6, lane = threadIdx.x & 63;
  if (bx < 8192) {                       // LN1: visual fp32 -> x bf16
    int row = bx * 4 + wave;
    size_t base = (size_t)row * 256 + lane * 4;
    float4 f = *reinterpret_cast<const float4*>(visual + base);
    float v0 = f.x, v1 = f.y, v2 = f.z, v3 = f.w;
    float s = v0 + v1 + v2 + v3;
    float q = v0 * v0 + v1 * v1 + v2 * v2 + v3 * v3;
#pragma unroll
    for (int off = 1; off < 64; off <<= 1) {
      s += __shfl_xor(s, off);
      q += __shfl_xor(q, off);
    }
    float mean = s * (1.0f / 256.0f);
    float var  = q * (1.0f / 256.0f) - mean * mean;
    float rstd = rsqrtf(var + 1e-5f);
    float4 gv = *reinterpret_cast<const float4*>(g1 + lane * 4);
    float4 bv4 = *reinterpret_cast<const float4*>(b1 + lane * 4);
    ushort4 o;
    o.x = f2b((v0 - mean) * rstd * gv.x + bv4.x);
    o.y = f2b((v1 - mean) * rstd * gv.y + bv4.y);
    o.z = f2b((v2 - mean) * rstd * gv.z + bv4.z);
    o.w = f2b((v3 - mean) * rstd * gv.w + bv4.w);
    *reinterpret_cast<ushort4*>(xbuf + base) = o;
    return;
  }
  if (bx >= 11778) {                     // pad mask: one wave per (b,t) row
    int row = (bx - 11778) * 4 + wave;   // 0..615
    const float* tr = text + (size_t)row * CT_ + lane * 8;
    float4 f0 = *reinterpret_cast<const float4*>(tr);
    float4 f1 = *reinterpret_cast<const float4*>(tr + 4);
    float s = fabsf(f0.x) + fabsf(f0.y) + fabsf(f0.z) + fabsf(f0.w)
            + fabsf(f1.x) + fabsf(f1.y) + fabsf(f1.z) + fabsf(f1.w);
#pragma unroll
    for (int off = 1; off < 64; off <<= 1) s += __shfl_xor(s, off);
    if (lane == 0) padb[row] = (s <= 1e-6f) ? 1.0f : 0.0f;
    return;
  }
  int gi = (bx - 8192) * 256 + threadIdx.x;
  const float* src; unsigned short* dst; int R, C, idx;
  if      (gi < 65536)  { src=s0; dst=d0; R=256;  C=256;  idx=gi; }
  else if (gi < 196608) { src=s1; dst=d1; R=512;  C=256;  idx=gi-65536; }
  else if (gi < 327680) { src=s2; dst=d2; R=512;  C=256;  idx=gi-196608; }
  else if (gi < 393216) { src=s3; dst=d3; R=256;  C=256;  idx=gi-327680; }
  else if (gi < 655360) { src=s4; dst=d4; R=256;  C=1024; idx=gi-393216; }
  else if (gi < 917504) { src=s5; dst=d5; R=1024; C=256;  idx=gi-655360; }
  else if (gi < 918016) {
    int i = gi - 917504;
    bkv[i] = (i < 256) ? bk[i] : bv[i - 256];
    return;
  } else return;
  int r = idx / C, c = idx - r * C;
  dst[(size_t)c * R + r] = f2b(src[idx]);
}

// ------------- fast MFMA GEMM (m97 structure): C[M,N] = A @ Bt^T ---------
// flags: bit0 out fp32, bit1 exact-GELU, bit3 resid fp32
template <int BN>
__global__ __launch_bounds__(256) void gemm_fast(
    const unsigned short* __restrict__ A, const unsigned short* __restrict__ Bt,
    const float* __restrict__ bias, const void* resid,
    const float* __restrict__ alpha_ptr, void* out,
    int M, int N, int K, int flags) {
  constexpr int NI  = BN / 32;
  constexpr int CHB = BN / 16;
  __shared__ unsigned short lA[128 * 32];
  __shared__ unsigned short lB[BN * 32];
  int tid = threadIdx.x;
  int bm = blockIdx.x * 128, bn = blockIdx.y * BN;
  int lane = tid & 63, wave = tid >> 6;
  int wm = (wave & 1) * 64, wn = (wave >> 1) * (BN / 2);
  int l15 = lane & 15, quad = lane >> 4;
  int crow = lane >> 2, ccol = (lane & 3) * 8;
  f32x4 acc[4][NI] = {};
  for (int k0 = 0; k0 < K; k0 += 32) {
#pragma unroll
    for (int ch = 0; ch < 2; ++ch) {
      int c = wave * 2 + ch;
      async_copy16(A + (size_t)(bm + c * 16 + crow) * K + k0 + ccol,
                   &lA[c * 512]);
    }
#pragma unroll
    for (int ch = wave; ch < CHB; ch += 4)
      async_copy16(Bt + (size_t)(bn + ch * 16 + crow) * K + k0 + ccol,
                   &lB[ch * 512]);
    __syncthreads();
    bf16x8 af[4], bfr[NI];
#pragma unroll
    for (int mi = 0; mi < 4; ++mi)
      af[mi] = *reinterpret_cast<const bf16x8*>(&lA[(wm + mi * 16 + l15) * 32 + quad * 8]);
#pragma unroll
    for (int ni = 0; ni < NI; ++ni)
      bfr[ni] = *reinterpret_cast<const bf16x8*>(&lB[(wn + ni * 16 + l15) * 32 + quad * 8]);
#pragma unroll
    for (int mi = 0; mi < 4; ++mi)
#pragma unroll
      for (int ni = 0; ni < NI; ++ni)
        acc[mi][ni] = __builtin_amdgcn_mfma_f32_16x16x32_bf16(af[mi], bfr[ni],
                                                              acc[mi][ni], 0, 0, 0);
    __syncthreads();
  }
  float alpha = alpha_ptr ? *alpha_ptr : 1.0f;
#pragma unroll
  for (int mi = 0; mi < 4; ++mi) {
#pragma unroll
    for (int ni = 0; ni < NI; ++ni) {
      int gcol = bn + wn + ni * 16 + l15;
      float bsf = bias ? bias[gcol] : 0.0f;
#pragma unroll
      for (int r = 0; r < 4; ++r) {
        int grow = bm + wm + mi * 16 + quad * 4 + r;
        float v = acc[mi][ni][r] + bsf;
        if (flags & 2) v = 0.5f * v * (1.0f + erff(v * 0.70710678118654752f));
        size_t oi = (size_t)grow * N + gcol;
        if (resid) {
          float rv = (flags & 8) ? ((const float*)resid)[oi]
                                 : bf2f(((const unsigned short*)resid)[oi]);
          v = rv + alpha * v;
        }
        if (flags & 1) ((float*)out)[oi] = v;
        else           ((unsigned short*)out)[oi] = f2b(v);
      }
    }
  }
}

// ---- fused o-proj + residual + LN2 (128 rows/block, full rows) ----------
__global__ __launch_bounds__(256) void gemm_oln(
    const unsigned short* __restrict__ A, const unsigned short* __restrict__ Bt,
    const float* __restrict__ bias, const unsigned short* __restrict__ xres,
    const float* __restrict__ alpha_ptr,
    const float* __restrict__ g2, const float* __restrict__ b2,
    unsigned short* __restrict__ ybf, float* __restrict__ yf32) {
  __shared__ unsigned short sm[32768];
  unsigned short* lA = sm;
  unsigned short* lB = sm + 4096;
  unsigned short* yt = sm;
  const int K = 256;
  int tid = threadIdx.x;
  int bm = blockIdx.x * 128;
  int lane = tid & 63, wave = tid >> 6;
  int wm = (wave & 1) * 64, wn = (wave >> 1) * 128;
  int l15 = lane & 15, quad = lane >> 4;
  int crow = lane >> 2, ccol = (lane & 3) * 8;
  f32x4 acc[4][8] = {};
  for (int k0 = 0; k0 < K; k0 += 32) {
#pragma unroll
    for (int ch = 0; ch < 2; ++ch) {
      int c = wave * 2 + ch;
      async_copy16(A + (size_t)(bm + c * 16 + crow) * K + k0 + ccol,
                   &lA[c * 512]);
    }
#pragma unroll
    for (int ch = wave; ch < 16; ch += 4)
      async_copy16(Bt + (size_t)(ch * 16 + crow) * K + k0 + ccol,
                   &lB[ch * 512]);
    __syncthreads();
    bf16x8 af[4], bfr[8];
#pragma unroll
    for (int mi = 0; mi < 4; ++mi)
      af[mi] = *reinterpret_cast<const bf16x8*>(&lA[(wm + mi * 16 + l15) * 32 + quad * 8]);
#pragma unroll
    for (int ni = 0; ni < 8; ++ni)
      bfr[ni] = *reinterpret_cast<const bf16x8*>(&lB[(wn + ni * 16 + l15) * 32 + quad * 8]);
#pragma unroll
    for (int mi = 0; mi < 4; ++mi)
#pragma unroll
      for (int ni = 0; ni < 8; ++ni)
        acc[mi][ni] = __builtin_amdgcn_mfma_f32_16x16x32_bf16(af[mi], bfr[ni],
                                                              acc[mi][ni], 0, 0, 0);
    __syncthreads();
  }
  float alpha = *alpha_ptr;
#pragma unroll
  for (int mi = 0; mi < 4; ++mi) {
#pragma unroll
    for (int ni = 0; ni < 8; ++ni) {
      int gcol = wn + ni * 16 + l15;
      float bsf = bias[gcol];
#pragma unroll
      for (int r = 0; r < 4; ++r) {
        int lrow = wm + mi * 16 + quad * 4 + r;
        float v = acc[mi][ni][r] + bsf;
        float y0 = bf2f(xres[(size_t)(bm + lrow) * 256 + gcol]) + alpha * v;
        yt[lrow * 256 + gcol] = f2b(y0);
      }
    }
  }
  __syncthreads();
  for (int it = 0; it < 32; ++it) {
    int row = wave * 32 + it;
    ushort4 u = *reinterpret_cast<const ushort4*>(&yt[row * 256 + lane * 4]);
    float v0 = bf2f(u.x), v1 = bf2f(u.y), v2 = bf2f(u.z), v3 = bf2f(u.w);
    float s = v0 + v1 + v2 + v3;
    float q = v0 * v0 + v1 * v1 + v2 * v2 + v3 * v3;
#pragma unroll
    for (int off = 1; off < 64; off <<= 1) {
      s += __shfl_xor(s, off);
      q += __shfl_xor(q, off);
    }
    float mean = s * (1.0f / 256.0f);
    float var  = q * (1.0f / 256.0f) - mean * mean;
    float rstd = rsqrtf(var + 1e-5f);
    float4 gv = *reinterpret_cast<const float4*>(g2 + lane * 4);
    float4 bv = *reinterpret_cast<const float4*>(b2 + lane * 4);
    float o0 = (v0 - mean) * rstd * gv.x + bv.x;
    float o1 = (v1 - mean) * rstd * gv.y + bv.y;
    float o2 = (v2 - mean) * rstd * gv.z + bv.z;
    float o3 = (v3 - mean) * rstd * gv.w + bv.w;
    size_t base = (size_t)(bm + row) * 256 + lane * 4;
    ushort4 ob;
    ob.x = f2b(o0); ob.y = f2b(o1); ob.z = f2b(o2); ob.w = f2b(o3);
    *reinterpret_cast<ushort4*>(ybf + base) = ob;
    *reinterpret_cast<float4*>(yf32 + base) = make_float4(o0, o1, o2, o3);
  }
}

// ------ kv GEMM: [k|v](616,512) = text @ [WkT;WvT]^T, split fp32 outputs --
__global__ __launch_bounds__(256) void gemm_kv(
    const float* __restrict__ A, const unsigned short* __restrict__ Bt,
    const float* __restrict__ bias, float* __restrict__ kout,
    float* __restrict__ vout) {
  __shared__ unsigned short lA[64 * 40];
  __shared__ unsigned short lB[64 * 40];
  const int M = BT_, K = CT_;
  int tid = threadIdx.x;
  int bm = blockIdx.x * 64, bn = blockIdx.y * 64;
  int srow = tid >> 2, sc8 = (tid & 3) * 8;
  int lane = tid & 63, wave = tid >> 6;
  int wm = (wave & 1) * 32, wn = (wave >> 1) * 32;
  int l15 = lane & 15, quad = lane >> 4;
  f32x4 acc[2][2] = {};
  int gm = bm + srow, gn = bn + srow;
  const bool aok = (gm < M);
  for (int k0 = 0; k0 < K; k0 += 32) {
    uint4 apk = make_uint4(0, 0, 0, 0);
    if (aok) {
      const float* Af = A + (size_t)gm * K + k0 + sc8;
      float4 f0 = *reinterpret_cast<const float4*>(Af);
      float4 f1 = *reinterpret_cast<const float4*>(Af + 4);
      apk.x = pack2(f0.x, f0.y); apk.y = pack2(f0.z, f0.w);
      apk.z = pack2(f1.x, f1.y); apk.w = pack2(f1.z, f1.w);
    }
    uint4 bpk = *reinterpret_cast<const uint4*>(Bt + (size_t)gn * K + k0 + sc8);
    *reinterpret_cast<uint4*>(&lA[srow * 40 + sc8]) = apk;
    *reinterpret_cast<uint4*>(&lB[srow * 40 + sc8]) = bpk;
    __syncthreads();
    bf16x8 a0 = *reinterpret_cast<const bf16x8*>(&lA[(wm + l15) * 40 + quad * 8]);
    bf16x8 a1 = *reinterpret_cast<const bf16x8*>(&lA[(wm + 16 + l15) * 40 + quad * 8]);
    bf16x8 b0 = *reinterpret_cast<const bf16x8*>(&lB[(wn + l15) * 40 + quad * 8]);
    bf16x8 b1 = *reinterpret_cast<const bf16x8*>(&lB[(wn + 16 + l15) * 40 + quad * 8]);
    acc[0][0] = __builtin_amdgcn_mfma_f32_16x16x32_bf16(a0, b0, acc[0][0], 0, 0, 0);
    acc[0][1] = __builtin_amdgcn_mfma_f32_16x16x32_bf16(a0, b1, acc[0][1], 0, 0, 0);
    acc[1][0] = __builtin_amdgcn_mfma_f32_16x16x32_bf16(a1, b0, acc[1][0], 0, 0, 0);
    acc[1][1] = __builtin_amdgcn_mfma_f32_16x16x32_bf16(a1, b1, acc[1][1], 0, 0, 0);
    __syncthreads();
  }
#pragma unroll
  for (int mt = 0; mt < 2; ++mt) {
#pragma unroll
    for (int nt = 0; nt < 2; ++nt) {
      int gcol = bn + wn + nt * 16 + l15;
      float bsf = bias[gcol];
#pragma unroll
      for (int r = 0; r < 4; ++r) {
        int grow = bm + wm + mt * 16 + quad * 4 + r;
        if (grow >= M) continue;
        float v = acc[mt][nt][r] + bsf;
        if (gcol < 256) kout[(size_t)grow * 256 + gcol] = v;
        else            vout[(size_t)grow * 256 + gcol - 256] = v;
      }
    }
  }
}

// ---------- attention v2: MFMA QK^T + top-5 + V gather -------------------
// grid (32, NH, B), 256 thr; block owns 128 query rows of head h, batch b.
// S[n,t] = raw_dot * rn_n * sc_t (norms factored); pad col -> -inf.
#define SSTR 81   // odd stride -> row-scan conflict-free
#define VSTR 33
__global__ __launch_bounds__(256) void attn_kernel(
    unsigned short* qa, const float* __restrict__ k,
    const float* __restrict__ v, const float* __restrict__ padb,
    const float* __restrict__ ls_ptr) {
  __shared__ unsigned short qb[128 * 32];   // 8 KB
  __shared__ unsigned short kb[80 * 32];    // 5 KB
  __shared__ float S[128 * SSTR];           // 41.5 KB
  __shared__ float vs[TT * VSTR];           // 10.2 KB
  __shared__ float rn[128];
  __shared__ float scs[80];
  __shared__ float ps[80];
  __shared__ int allpad_s;
  int tid = threadIdx.x, lane = tid & 63, wave = tid >> 6;
  int h = blockIdx.y, b = blockIdx.z;
  size_t qbase = ((size_t)b * NPIX + blockIdx.x * 128) * CV_ + h * DH_;
  size_t kvbase = (size_t)b * TT * CV_ + h * DH_;
  // stage q (async, 16 rows per wave-issue; row = 64 B = 4 lanes)
#pragma unroll
  for (int i = 0; i < 2; ++i) {
    int c = wave * 2 + i;                   // chunk of 16 rows
    int row = c * 16 + (lane >> 2), sub = (lane & 3) * 8;
    async_copy16(qa + qbase + (size_t)row * CV_ + sub, &qb[c * 512]);
  }
  // stage k (fp32 -> bf16), rows 77..79 zero
  for (int j = tid; j < 80 * 32; j += 256) {
    int t = j >> 5, d = j & 31;
    float val = (t < TT) ? k[kvbase + (size_t)t * CV_ + d] : 0.0f;
    kb[j] = f2b(val);
  }
  // stage v (fp32)
  for (int j = tid; j < TT * 32; j += 256) {
    int t = j >> 5, d = j & 31;
    vs[t * VSTR + d] = v[kvbase + (size_t)t * CV_ + d];
  }
  if (tid < 80) ps[tid] = (tid < TT) ? padb[b * TT + tid] : 1.0f;
  if (tid == 0) allpad_s = 1;
  __syncthreads();
  // per-row q scale and per-col k scale
  float ls = *ls_ptr;
  ls = fminf(fmaxf(ls, -2.0f), 2.0f);
  float scale = expf(ls) * 0.17677669529663687f;   // exp(clip)/sqrt(32)
  if (tid < 128) {
    float ssum = 0.f;
#pragma unroll
    for (int d = 0; d < 32; ++d) { float x = bf2f(qb[tid * 32 + d]); ssum += x * x; }
    rn[tid] = scale / fmaxf(sqrtf(ssum), 1e-6f);
  } else if (tid < 208) {
    int t = tid - 128;
    if (t < TT && ps[t] == 0.0f) {
      float ssum = 0.f;
#pragma unroll
      for (int d = 0; d < 32; ++d) { float x = bf2f(kb[t * 32 + d]); ssum += x * x; }
      scs[t] = 1.0f / fmaxf(sqrtf(ssum), 1e-6f);
      allpad_s = 0;
    } else {
      scs[t] = 0.0f;
    }
  }
  __syncthreads();
  // MFMA: S = Q(128x32) @ K^T(32x80); wave owns 32 rows x 80 cols
  {
    int wm = wave * 32;
    int l15 = lane & 15, quad = lane >> 4;
    f32x4 acc[2][5] = {};
    bf16x8 af[2], bfr[5];
#pragma unroll
    for (int mi = 0; mi < 2; ++mi)
      af[mi] = *reinterpret_cast<const bf16x8*>(&qb[(wm + mi * 16 + l15) * 32 + quad * 8]);
#pragma unroll
    for (int ni = 0; ni < 5; ++ni)
      bfr[ni] = *reinterpret_cast<const bf16x8*>(&kb[(ni * 16 + l15) * 32 + quad * 8]);
#pragma unroll
    for (int mi = 0; mi < 2; ++mi)
#pragma unroll
      for (int ni = 0; ni < 5; ++ni)
        acc[mi][ni] = __builtin_amdgcn_mfma_f32_16x16x32_bf16(af[mi], bfr[ni],
                                                              acc[mi][ni], 0, 0, 0);
#pragma unroll
    for (int mi = 0; mi < 2; ++mi) {
#pragma unroll
      for (int ni = 0; ni < 5; ++ni) {
        int col = ni * 16 + l15;
        float sc = scs[col];
#pragma unroll
        for (int r = 0; r < 4; ++r) {
          int row = wm + mi * 16 + quad * 4 + r;
          float val = (sc > 0.0f) ? acc[mi][ni][r] * rn[row] * sc : -INFINITY;
          S[row * SSTR + col] = val;
        }
      }
    }
  }
  __syncthreads();
  int allpad = allpad_s;
  // phase B: thread pair per row; both scan all 77 (broadcast reads)
  int row = tid >> 1, dhalf = tid & 1;
  const float* Srow = &S[row * SSTR];
  float tv0 = -INFINITY, tv1 = -INFINITY, tv2 = -INFINITY, tv3 = -INFINITY, tv4 = -INFINITY;
  int   ti0 = 0, ti1 = 0, ti2 = 0, ti3 = 0, ti4 = 0;
  for (int t = 0; t < TT; ++t) {
    float sdot = Srow[t];
    bool g0 = sdot > tv0, g1 = sdot > tv1, g2 = sdot > tv2,
         g3 = sdot > tv3, g4 = sdot > tv4;
    tv4 = g4 ? (g3 ? tv3 : sdot) : tv4;  ti4 = g4 ? (g3 ? ti3 : t) : ti4;
    tv3 = g3 ? (g2 ? tv2 : sdot) : tv3;  ti3 = g3 ? (g2 ? ti2 : t) : ti3;
    tv2 = g2 ? (g1 ? tv1 : sdot) : tv2;  ti2 = g2 ? (g1 ? ti1 : t) : ti2;
    tv1 = g1 ? (g0 ? tv0 : sdot) : tv1;  ti1 = g1 ? (g0 ? ti0 : t) : ti1;
    tv0 = g0 ? sdot : tv0;               ti0 = g0 ? t : ti0;
  }
  float o[16];
#pragma unroll
  for (int d = 0; d < 16; ++d) o[d] = 0.f;
  if (!allpad && tv0 > -INFINITY) {
    float e0 = 1.0f;
    float e1 = expf(tv1 - tv0);
    float e2 = expf(tv2 - tv0);
    float e3 = expf(tv3 - tv0);
    float e4 = expf(tv4 - tv0);
    float inv = 1.0f / (e0 + e1 + e2 + e3 + e4);
    const float* v0p = &vs[ti0 * VSTR + dhalf * 16];
    const float* v1p = &vs[ti1 * VSTR + dhalf * 16];
    const float* v2p = &vs[ti2 * VSTR + dhalf * 16];
    const float* v3p = &vs[ti3 * VSTR + dhalf * 16];
    const float* v4p = &vs[ti4 * VSTR + dhalf * 16];
#pragma unroll
    for (int d = 0; d < 16; ++d)
      o[d] = (e0 * v0p[d] + e1 * v1p[d] + e2 * v2p[d] + e3 * v3p[d] + e4 * v4p[d]) * inv;
  }
  unsigned short* qp = qa + qbase + (size_t)row * CV_ + dhalf * 16;
#pragma unroll
  for (int i = 0; i < 4; ++i) {
    ushort4 u;
    u.x = f2b(o[4 * i]);     u.y = f2b(o[4 * i + 1]);
    u.z = f2b(o[4 * i + 2]); u.w = f2b(o[4 * i + 3]);
    reinterpret_cast<ushort4*>(qp)[i] = u;
  }
}

extern "C" void kernel_launch(void* const* d_in, const int* in_sizes, int n_in,
                              void* d_out, int out_size, void* d_ws, size_t ws_size,
                              hipStream_t stream) {
  const float* visual = (const float*)d_in[0];
  const float* text   = (const float*)d_in[1];
  const float* Wq  = (const float*)d_in[2];
  const float* bq  = (const float*)d_in[3];
  const float* Wk  = (const float*)d_in[4];
  const float* bk  = (const float*)d_in[5];
  const float* Wv  = (const float*)d_in[6];
  const float* bv  = (const float*)d_in[7];
  const float* Wo  = (const float*)d_in[8];
  const float* bo  = (const float*)d_in[9];
  const float* g1  = (const float*)d_in[10];
  const float* b1  = (const float*)d_in[11];
  const float* g2  = (const float*)d_in[12];
  const float* b2  = (const float*)d_in[13];
  const float* W1  = (const float*)d_in[14];
  const float* bf1 = (const float*)d_in[15];
  const float* W2  = (const float*)d_in[16];
  const float* bff2 = (const float*)d_in[17];
  const float* lsc = (const float*)d_in[18];
  const float* alp = (const float*)d_in[19];

  char* ws = (char*)d_ws;
  size_t off = 0;
  auto alloc = [&](size_t bytes) -> char* {
    char* p = ws + off;
    off += (bytes + 255) & ~(size_t)255;
    return p;
  };
  unsigned short* WqT = (unsigned short*)alloc((size_t)65536 * 2);
  unsigned short* WkT = (unsigned short*)alloc((size_t)131072 * 2);  // contiguous
  unsigned short* WvT = (unsigned short*)alloc((size_t)131072 * 2);  // with WkT
  unsigned short* WoT = (unsigned short*)alloc((size_t)65536 * 2);
  unsigned short* W1T = (unsigned short*)alloc((size_t)262144 * 2);
  unsigned short* W2T = (unsigned short*)alloc((size_t)262144 * 2);
  float*          bkv  = (float*)alloc(512 * 4);
  float*          kbuf = (float*)alloc((size_t)BT_ * CV_ * 4);
  float*          vbuf = (float*)alloc((size_t)BT_ * CV_ * 4);
  float*          padb = (float*)alloc((size_t)BT_ * 4);
  char* U = ws + off;
  unsigned short* xbuf = (unsigned short*)U;
  unsigned short* qbuf = (unsigned short*)(U + 16777216);
  unsigned short* hbuf = (unsigned short*)(U + 16777216);
  float*          ybuf = (float*)d_out;
  bool fullFFN = (ws_size >= off + (size_t)16777216 + (size_t)67108864);

  // 1. prep: LN1 + weight convT + kv bias + pad mask
  prep_kernel<<<11932, 256, 0, stream>>>(visual, g1, b1, xbuf,
                                         Wq, Wk, Wv, Wo, W1, W2,
                                         WqT, WkT, WvT, WoT, W1T, W2T,
                                         bk, bv, bkv, text, padb);
  // 2. q = x @ Wq + bq  (bf16)
  gemm_fast<128><<<dim3(256, 2), 256, 0, stream>>>(
      xbuf, WqT, bq, nullptr, nullptr, qbuf, MROW, 256, 256, 0);
  // 3. k|v = text @ [WkT;WvT]^T + bkv  (fp32 split outputs)
  gemm_kv<<<dim3(10, 8), 256, 0, stream>>>(text, WkT, bkv, kbuf, vbuf);
  // 4. attention v2 (MFMA scores): qbuf -> qbuf in place
  attn_kernel<<<dim3(32, NH_, NB), 256, 0, stream>>>(qbuf, kbuf, vbuf, padb, lsc);
  // 5. fused o-proj + residual + LN2: y bf16 (xbuf) + y fp32 (d_out)
  gemm_oln<<<256, 256, 0, stream>>>(qbuf, WoT, bo, xbuf, alp, g2, b2,
                                    xbuf, ybuf);
  // 6+7. FFN
  if (fullFFN) {
    gemm_fast<128><<<dim3(256, 8), 256, 0, stream>>>(
        xbuf, W1T, bf1, nullptr, nullptr, hbuf, MROW, 1024, 256, 2);
    gemm_fast<64><<<dim3(256, 4), 256, 0, stream>>>(
        hbuf, W2T, bff2, ybuf, nullptr, (void*)ybuf, MROW, 256, 1024, 1 | 8);
  } else {
    for (int half = 0; half < 2; ++half) {
      const unsigned short* xh = xbuf + (size_t)half * 16384 * CV_;
      const float* yh = ybuf + (size_t)half * 16384 * CV_;
      gemm_fast<128><<<dim3(128, 8), 256, 0, stream>>>(
          xh, W1T, bf1, nullptr, nullptr, hbuf, 16384, 1024, 256, 2);
      gemm_fast<64><<<dim3(128, 4), 256, 0, stream>>>(
          hbuf, W2T, bff2, yh, nullptr, (void*)yh, 16384, 256, 1024, 1 | 8);
    }
  }
}

// Round 8
// 331.276 us; speedup vs baseline: 1.0609x; 1.0609x over previous
//
#include <hip/hip_runtime.h>
#include <math.h>

// Problem constants
#define NB   8
#define NPIX 4096          // H*W
#define MROW 32768         // B*H*W
#define CV_  256
#define TT   77
#define CT_  512
#define NH_  8
#define DH_  32
#define BT_  616           // B*T

typedef __bf16 bf16x8 __attribute__((ext_vector_type(8)));
typedef float  f32x4  __attribute__((ext_vector_type(4)));

__device__ __forceinline__ float bf2f(unsigned short u) {
  return __uint_as_float(((unsigned)u) << 16);
}
__device__ __forceinline__ unsigned short f2b(float f) {
  unsigned u = __float_as_uint(f);
  return (unsigned short)((u + 0x7FFFu + ((u >> 16) & 1u)) >> 16);
}
__device__ __forceinline__ unsigned pack2(float lo, float hi) {
  return ((unsigned)f2b(hi) << 16) | (unsigned)f2b(lo);
}
__device__ __forceinline__ void async_copy16(const unsigned short* g,
                                             unsigned short* l) {
  __builtin_amdgcn_global_load_lds(
      (const __attribute__((address_space(1))) void*)g,
      (__attribute__((address_space(3))) void*)l, 16, 0, 0);
}

// -- prep: LN1 (0..8191) + weight convT + kv bias (..11777) + pad (..11931) --
__global__ __launch_bounds__(256) void prep_kernel(
    const float* __restrict__ visual, const float* __restrict__ g1,
    const float* __restrict__ b1, unsigned short* __restrict__ xbuf,
    const float* __restrict__ s0, const float* __restrict__ s1,
    const float* __restrict__ s2, const float* __restrict__ s3,
    const float* __restrict__ s4, const float* __restrict__ s5,
    unsigned short* __restrict__ d0, unsigned short* __restrict__ d1,
    unsigned short* __restrict__ d2, unsigned short* __restrict__ d3,
    unsigned short* __restrict__ d4, unsigned short* __restrict__ d5,
    const float* __restrict__ bk, const float* __restrict__ bv,
    float* __restrict__ bkv, const float* __restrict__ text,
    float* __restrict__ padb) {
  int bx = blockIdx.x;
  int wave = threadIdx.x >> 6, lane = threadIdx.x & 63;
  if (bx < 8192) {                       // LN1: visual fp32 -> x bf16
    int row = bx * 4 + wave;
    size_t base = (size_t)row * 256 + lane * 4;
    float4 f = *reinterpret_cast<const float4*>(visual + base);
    float v0 = f.x, v1 = f.y, v2 = f.z, v3 = f.w;
    float s = v0 + v1 + v2 + v3;
    float q = v0 * v0 + v1 * v1 + v2 * v2 + v3 * v3;
#pragma unroll
    for (int off = 1; off < 64; off <<= 1) {
      s += __shfl_xor(s, off);
      q += __shfl_xor(q, off);
    }
    float mean = s * (1.0f / 256.0f);
    float var  = q * (1.0f / 256.0f) - mean * mean;
    float rstd = rsqrtf(var + 1e-5f);
    float4 gv = *reinterpret_cast<const float4*>(g1 + lane * 4);
    float4 bv4 = *reinterpret_cast<const float4*>(b1 + lane * 4);
    ushort4 o;
    o.x = f2b((v0 - mean) * rstd * gv.x + bv4.x);
    o.y = f2b((v1 - mean) * rstd * gv.y + bv4.y);
    o.z = f2b((v2 - mean) * rstd * gv.z + bv4.z);
    o.w = f2b((v3 - mean) * rstd * gv.w + bv4.w);
    *reinterpret_cast<ushort4*>(xbuf + base) = o;
    return;
  }
  if (bx >= 11778) {                     // pad mask: one wave per (b,t) row
    int row = (bx - 11778) * 4 + wave;   // 0..615
    const float* tr = text + (size_t)row * CT_ + lane * 8;
    float4 f0 = *reinterpret_cast<const float4*>(tr);
    float4 f1 = *reinterpret_cast<const float4*>(tr + 4);
    float s = fabsf(f0.x) + fabsf(f0.y) + fabsf(f0.z) + fabsf(f0.w)
            + fabsf(f1.x) + fabsf(f1.y) + fabsf(f1.z) + fabsf(f1.w);
#pragma unroll
    for (int off = 1; off < 64; off <<= 1) s += __shfl_xor(s, off);
    if (lane == 0) padb[row] = (s <= 1e-6f) ? 1.0f : 0.0f;
    return;
  }
  int gi = (bx - 8192) * 256 + threadIdx.x;
  const float* src; unsigned short* dst; int R, C, idx;
  if      (gi < 65536)  { src=s0; dst=d0; R=256;  C=256;  idx=gi; }
  else if (gi < 196608) { src=s1; dst=d1; R=512;  C=256;  idx=gi-65536; }
  else if (gi < 327680) { src=s2; dst=d2; R=512;  C=256;  idx=gi-196608; }
  else if (gi < 393216) { src=s3; dst=d3; R=256;  C=256;  idx=gi-327680; }
  else if (gi < 655360) { src=s4; dst=d4; R=256;  C=1024; idx=gi-393216; }
  else if (gi < 917504) { src=s5; dst=d5; R=1024; C=256;  idx=gi-655360; }
  else if (gi < 918016) {
    int i = gi - 917504;
    bkv[i] = (i < 256) ? bk[i] : bv[i - 256];
    return;
  } else return;
  int r = idx / C, c = idx - r * C;
  dst[(size_t)c * R + r] = f2b(src[idx]);
}

// ------------- fast MFMA GEMM (m97 structure): C[M,N] = A @ Bt^T ---------
// flags: bit0 out fp32, bit1 exact-GELU, bit3 resid fp32
template <int BN>
__global__ __launch_bounds__(256) void gemm_fast(
    const unsigned short* __restrict__ A, const unsigned short* __restrict__ Bt,
    const float* __restrict__ bias, const void* resid,
    const float* __restrict__ alpha_ptr, void* out,
    int M, int N, int K, int flags) {
  constexpr int NI  = BN / 32;
  constexpr int CHB = BN / 16;
  __shared__ unsigned short lA[128 * 32];
  __shared__ unsigned short lB[BN * 32];
  int tid = threadIdx.x;
  int bm = blockIdx.x * 128, bn = blockIdx.y * BN;
  int lane = tid & 63, wave = tid >> 6;
  int wm = (wave & 1) * 64, wn = (wave >> 1) * (BN / 2);
  int l15 = lane & 15, quad = lane >> 4;
  int crow = lane >> 2, ccol = (lane & 3) * 8;
  f32x4 acc[4][NI] = {};
  for (int k0 = 0; k0 < K; k0 += 32) {
#pragma unroll
    for (int ch = 0; ch < 2; ++ch) {
      int c = wave * 2 + ch;
      async_copy16(A + (size_t)(bm + c * 16 + crow) * K + k0 + ccol,
                   &lA[c * 512]);
    }
#pragma unroll
    for (int ch = wave; ch < CHB; ch += 4)
      async_copy16(Bt + (size_t)(bn + ch * 16 + crow) * K + k0 + ccol,
                   &lB[ch * 512]);
    __syncthreads();
    bf16x8 af[4], bfr[NI];
#pragma unroll
    for (int mi = 0; mi < 4; ++mi)
      af[mi] = *reinterpret_cast<const bf16x8*>(&lA[(wm + mi * 16 + l15) * 32 + quad * 8]);
#pragma unroll
    for (int ni = 0; ni < NI; ++ni)
      bfr[ni] = *reinterpret_cast<const bf16x8*>(&lB[(wn + ni * 16 + l15) * 32 + quad * 8]);
#pragma unroll
    for (int mi = 0; mi < 4; ++mi)
#pragma unroll
      for (int ni = 0; ni < NI; ++ni)
        acc[mi][ni] = __builtin_amdgcn_mfma_f32_16x16x32_bf16(af[mi], bfr[ni],
                                                              acc[mi][ni], 0, 0, 0);
    __syncthreads();
  }
  float alpha = alpha_ptr ? *alpha_ptr : 1.0f;
#pragma unroll
  for (int mi = 0; mi < 4; ++mi) {
#pragma unroll
    for (int ni = 0; ni < NI; ++ni) {
      int gcol = bn + wn + ni * 16 + l15;
      float bsf = bias ? bias[gcol] : 0.0f;
#pragma unroll
      for (int r = 0; r < 4; ++r) {
        int grow = bm + wm + mi * 16 + quad * 4 + r;
        float v = acc[mi][ni][r] + bsf;
        if (flags & 2) v = 0.5f * v * (1.0f + erff(v * 0.70710678118654752f));
        size_t oi = (size_t)grow * N + gcol;
        if (resid) {
          float rv = (flags & 8) ? ((const float*)resid)[oi]
                                 : bf2f(((const unsigned short*)resid)[oi]);
          v = rv + alpha * v;
        }
        if (flags & 1) ((float*)out)[oi] = v;
        else           ((unsigned short*)out)[oi] = f2b(v);
      }
    }
  }
}

// ---- fused o-proj + residual + LN2 (128 rows/block, full rows) ----------
__global__ __launch_bounds__(256) void gemm_oln(
    const unsigned short* __restrict__ A, const unsigned short* __restrict__ Bt,
    const float* __restrict__ bias, const unsigned short* __restrict__ xres,
    const float* __restrict__ alpha_ptr,
    const float* __restrict__ g2, const float* __restrict__ b2,
    unsigned short* __restrict__ ybf, float* __restrict__ yf32) {
  __shared__ unsigned short sm[32768];
  unsigned short* lA = sm;
  unsigned short* lB = sm + 4096;
  unsigned short* yt = sm;
  const int K = 256;
  int tid = threadIdx.x;
  int bm = blockIdx.x * 128;
  int lane = tid & 63, wave = tid >> 6;
  int wm = (wave & 1) * 64, wn = (wave >> 1) * 128;
  int l15 = lane & 15, quad = lane >> 4;
  int crow = lane >> 2, ccol = (lane & 3) * 8;
  f32x4 acc[4][8] = {};
  for (int k0 = 0; k0 < K; k0 += 32) {
#pragma unroll
    for (int ch = 0; ch < 2; ++ch) {
      int c = wave * 2 + ch;
      async_copy16(A + (size_t)(bm + c * 16 + crow) * K + k0 + ccol,
                   &lA[c * 512]);
    }
#pragma unroll
    for (int ch = wave; ch < 16; ch += 4)
      async_copy16(Bt + (size_t)(ch * 16 + crow) * K + k0 + ccol,
                   &lB[ch * 512]);
    __syncthreads();
    bf16x8 af[4], bfr[8];
#pragma unroll
    for (int mi = 0; mi < 4; ++mi)
      af[mi] = *reinterpret_cast<const bf16x8*>(&lA[(wm + mi * 16 + l15) * 32 + quad * 8]);
#pragma unroll
    for (int ni = 0; ni < 8; ++ni)
      bfr[ni] = *reinterpret_cast<const bf16x8*>(&lB[(wn + ni * 16 + l15) * 32 + quad * 8]);
#pragma unroll
    for (int mi = 0; mi < 4; ++mi)
#pragma unroll
      for (int ni = 0; ni < 8; ++ni)
        acc[mi][ni] = __builtin_amdgcn_mfma_f32_16x16x32_bf16(af[mi], bfr[ni],
                                                              acc[mi][ni], 0, 0, 0);
    __syncthreads();
  }
  float alpha = *alpha_ptr;
#pragma unroll
  for (int mi = 0; mi < 4; ++mi) {
#pragma unroll
    for (int ni = 0; ni < 8; ++ni) {
      int gcol = wn + ni * 16 + l15;
      float bsf = bias[gcol];
#pragma unroll
      for (int r = 0; r < 4; ++r) {
        int lrow = wm + mi * 16 + quad * 4 + r;
        float v = acc[mi][ni][r] + bsf;
        float y0 = bf2f(xres[(size_t)(bm + lrow) * 256 + gcol]) + alpha * v;
        yt[lrow * 256 + gcol] = f2b(y0);
      }
    }
  }
  __syncthreads();
  for (int it = 0; it < 32; ++it) {
    int row = wave * 32 + it;
    ushort4 u = *reinterpret_cast<const ushort4*>(&yt[row * 256 + lane * 4]);
    float v0 = bf2f(u.x), v1 = bf2f(u.y), v2 = bf2f(u.z), v3 = bf2f(u.w);
    float s = v0 + v1 + v2 + v3;
    float q = v0 * v0 + v1 * v1 + v2 * v2 + v3 * v3;
#pragma unroll
    for (int off = 1; off < 64; off <<= 1) {
      s += __shfl_xor(s, off);
      q += __shfl_xor(q, off);
    }
    float mean = s * (1.0f / 256.0f);
    float var  = q * (1.0f / 256.0f) - mean * mean;
    float rstd = rsqrtf(var + 1e-5f);
    float4 gv = *reinterpret_cast<const float4*>(g2 + lane * 4);
    float4 bv = *reinterpret_cast<const float4*>(b2 + lane * 4);
    float o0 = (v0 - mean) * rstd * gv.x + bv.x;
    float o1 = (v1 - mean) * rstd * gv.y + bv.y;
    float o2 = (v2 - mean) * rstd * gv.z + bv.z;
    float o3 = (v3 - mean) * rstd * gv.w + bv.w;
    size_t base = (size_t)(bm + row) * 256 + lane * 4;
    ushort4 ob;
    ob.x = f2b(o0); ob.y = f2b(o1); ob.z = f2b(o2); ob.w = f2b(o3);
    *reinterpret_cast<ushort4*>(ybf + base) = ob;
    *reinterpret_cast<float4*>(yf32 + base) = make_float4(o0, o1, o2, o3);
  }
}

// ------ kv GEMM: [k|v](616,512) = text @ [WkT;WvT]^T, split fp32 outputs --
__global__ __launch_bounds__(256) void gemm_kv(
    const float* __restrict__ A, const unsigned short* __restrict__ Bt,
    const float* __restrict__ bias, float* __restrict__ kout,
    float* __restrict__ vout) {
  __shared__ unsigned short lA[64 * 40];
  __shared__ unsigned short lB[64 * 40];
  const int M = BT_, K = CT_;
  int tid = threadIdx.x;
  int bm = blockIdx.x * 64, bn = blockIdx.y * 64;
  int srow = tid >> 2, sc8 = (tid & 3) * 8;
  int lane = tid & 63, wave = tid >> 6;
  int wm = (wave & 1) * 32, wn = (wave >> 1) * 32;
  int l15 = lane & 15, quad = lane >> 4;
  f32x4 acc[2][2] = {};
  int gm = bm + srow, gn = bn + srow;
  const bool aok = (gm < M);
  for (int k0 = 0; k0 < K; k0 += 32) {
    uint4 apk = make_uint4(0, 0, 0, 0);
    if (aok) {
      const float* Af = A + (size_t)gm * K + k0 + sc8;
      float4 f0 = *reinterpret_cast<const float4*>(Af);
      float4 f1 = *reinterpret_cast<const float4*>(Af + 4);
      apk.x = pack2(f0.x, f0.y); apk.y = pack2(f0.z, f0.w);
      apk.z = pack2(f1.x, f1.y); apk.w = pack2(f1.z, f1.w);
    }
    uint4 bpk = *reinterpret_cast<const uint4*>(Bt + (size_t)gn * K + k0 + sc8);
    *reinterpret_cast<uint4*>(&lA[srow * 40 + sc8]) = apk;
    *reinterpret_cast<uint4*>(&lB[srow * 40 + sc8]) = bpk;
    __syncthreads();
    bf16x8 a0 = *reinterpret_cast<const bf16x8*>(&lA[(wm + l15) * 40 + quad * 8]);
    bf16x8 a1 = *reinterpret_cast<const bf16x8*>(&lA[(wm + 16 + l15) * 40 + quad * 8]);
    bf16x8 b0 = *reinterpret_cast<const bf16x8*>(&lB[(wn + l15) * 40 + quad * 8]);
    bf16x8 b1 = *reinterpret_cast<const bf16x8*>(&lB[(wn + 16 + l15) * 40 + quad * 8]);
    acc[0][0] = __builtin_amdgcn_mfma_f32_16x16x32_bf16(a0, b0, acc[0][0], 0, 0, 0);
    acc[0][1] = __builtin_amdgcn_mfma_f32_16x16x32_bf16(a0, b1, acc[0][1], 0, 0, 0);
    acc[1][0] = __builtin_amdgcn_mfma_f32_16x16x32_bf16(a1, b0, acc[1][0], 0, 0, 0);
    acc[1][1] = __builtin_amdgcn_mfma_f32_16x16x32_bf16(a1, b1, acc[1][1], 0, 0, 0);
    __syncthreads();
  }
#pragma unroll
  for (int mt = 0; mt < 2; ++mt) {
#pragma unroll
    for (int nt = 0; nt < 2; ++nt) {
      int gcol = bn + wn + nt * 16 + l15;
      float bsf = bias[gcol];
#pragma unroll
      for (int r = 0; r < 4; ++r) {
        int grow = bm + wm + mt * 16 + quad * 4 + r;
        if (grow >= M) continue;
        float v = acc[mt][nt][r] + bsf;
        if (gcol < 256) kout[(size_t)grow * 256 + gcol] = v;
        else            vout[(size_t)grow * 256 + gcol - 256] = v;
      }
    }
  }
}

// ---------- attention v3: MFMA QK^T + packed-index top-5 ------------------
// grid (64, NH, B), 256 thr; block owns 64 query rows of head h, batch b.
// Scores packed as (bits & ~0x7F) | col -> top-5 carries its own index.
#define SSTR 83   // write <=2-way, scan conflict-free
#define VSTR 33
#define NEGBIG -3.0e38f
__device__ __forceinline__ void ins5(float sv, float& tv0, float& tv1,
                                     float& tv2, float& tv3, float& tv4) {
  bool g0 = sv > tv0, g1 = sv > tv1, g2 = sv > tv2, g3 = sv > tv3, g4 = sv > tv4;
  tv4 = g4 ? (g3 ? tv3 : sv) : tv4;
  tv3 = g3 ? (g2 ? tv2 : sv) : tv3;
  tv2 = g2 ? (g1 ? tv1 : sv) : tv2;
  tv1 = g1 ? (g0 ? tv0 : sv) : tv1;
  tv0 = g0 ? sv : tv0;
}
__global__ __launch_bounds__(256) void attn_kernel(
    unsigned short* qa, const float* __restrict__ k,
    const float* __restrict__ v, const float* __restrict__ padb,
    const float* __restrict__ ls_ptr) {
  __shared__ unsigned short qb[64 * 40];    // 5.1 KB (stride 40: 16B-aligned)
  __shared__ unsigned short kb[80 * 40];    // 6.4 KB
  __shared__ float S[64 * SSTR];            // 21.2 KB
  __shared__ float vs[TT * VSTR];           // 10.2 KB
  __shared__ float rn[64];
  __shared__ float scs[80];
  __shared__ int allpad_s;
  int tid = threadIdx.x;
  int h = blockIdx.y, b = blockIdx.z;
  size_t qbase = ((size_t)b * NPIX + blockIdx.x * 64) * CV_ + h * DH_;
  size_t kvbase = (size_t)b * TT * CV_ + h * DH_;
  float ls = *ls_ptr;
  ls = fminf(fmaxf(ls, -2.0f), 2.0f);
  float scale = expf(ls) * 0.17677669529663687f;   // exp(clip)/sqrt(32)
  if (tid == 0) allpad_s = 1;
  __syncthreads();
  // --- q stage + q-norm: row=tid>>2, qq=tid&3 owns 8 bf16 (16B) ---
  int qrow = tid >> 2, qq = tid & 3;
  uint4 qv4 = *reinterpret_cast<const uint4*>(qa + qbase + (size_t)qrow * CV_ + qq * 8);
  *reinterpret_cast<uint4*>(&qb[qrow * 40 + qq * 8]) = qv4;
  {
    float ssq = 0.f;
    unsigned w[4] = {qv4.x, qv4.y, qv4.z, qv4.w};
#pragma unroll
    for (int i = 0; i < 4; ++i) {
      float a = bf2f((unsigned short)(w[i] & 0xFFFF));
      float bb = bf2f((unsigned short)(w[i] >> 16));
      ssq += a * a + bb * bb;
    }
    ssq += __shfl_xor(ssq, 1);
    ssq += __shfl_xor(ssq, 2);
    if (qq == 0) rn[qrow] = scale / fmaxf(sqrtf(ssq), 1e-6f);
  }
  // --- k stage (fp32->bf16) + k-norm: threads 0..153 ---
  if (tid < 154) {
    int kr = tid >> 1, kh = tid & 1;
    const float* kp = k + kvbase + (size_t)kr * CV_ + kh * 16;
    float4 f0 = *reinterpret_cast<const float4*>(kp);
    float4 f1 = *reinterpret_cast<const float4*>(kp + 4);
    float4 f2 = *reinterpret_cast<const float4*>(kp + 8);
    float4 f3 = *reinterpret_cast<const float4*>(kp + 12);
    float ks2 = f0.x*f0.x + f0.y*f0.y + f0.z*f0.z + f0.w*f0.w
              + f1.x*f1.x + f1.y*f1.y + f1.z*f1.z + f1.w*f1.w
              + f2.x*f2.x + f2.y*f2.y + f2.z*f2.z + f2.w*f2.w
              + f3.x*f3.x + f3.y*f3.y + f3.z*f3.z + f3.w*f3.w;
    uint4 p0, p1;
    p0.x = pack2(f0.x, f0.y); p0.y = pack2(f0.z, f0.w);
    p0.z = pack2(f1.x, f1.y); p0.w = pack2(f1.z, f1.w);
    p1.x = pack2(f2.x, f2.y); p1.y = pack2(f2.z, f2.w);
    p1.z = pack2(f3.x, f3.y); p1.w = pack2(f3.z, f3.w);
    *reinterpret_cast<uint4*>(&kb[kr * 40 + kh * 16]) = p0;
    *reinterpret_cast<uint4*>(&kb[kr * 40 + kh * 16 + 8]) = p1;
    ks2 += __shfl_xor(ks2, 1);
    if (kh == 0) {
      float p = padb[b * TT + kr];
      float sc = (p == 0.0f) ? 1.0f / fmaxf(sqrtf(ks2), 1e-6f) : 0.0f;
      scs[kr] = sc;
      if (sc > 0.0f) allpad_s = 0;
    }
  } else if (tid < 157) {
    scs[77 + (tid - 154)] = 0.0f;
  } else if (tid >= 160 && tid < 172) {
    int i = tid - 160;                 // zero kb rows 77..79 (data region)
    *reinterpret_cast<uint4*>(&kb[(77 + (i >> 2)) * 40 + (i & 3) * 8]) =
        make_uint4(0, 0, 0, 0);
  }
  // --- v stage (fp32, scalar writes into stride-33) ---
  for (int j = tid; j < TT * 8; j += 256) {
    int t = j >> 3, d4 = j & 7;
    float4 f = *reinterpret_cast<const float4*>(
        v + kvbase + (size_t)t * CV_ + d4 * 4);
    float* vp = &vs[t * VSTR + d4 * 4];
    vp[0] = f.x; vp[1] = f.y; vp[2] = f.z; vp[3] = f.w;
  }
  __syncthreads();
  // --- MFMA: S = Q(64x32) @ K^T(32x80); wave owns 16 rows x 80 cols ---
  {
    int lane = tid & 63, wave = tid >> 6;
    int wm = wave * 16;
    int l15 = lane & 15, quad = lane >> 4;
    f32x4 acc[5] = {};
    bf16x8 af = *reinterpret_cast<const bf16x8*>(&qb[(wm + l15) * 40 + quad * 8]);
    bf16x8 bfr[5];
#pragma unroll
    for (int ni = 0; ni < 5; ++ni)
      bfr[ni] = *reinterpret_cast<const bf16x8*>(&kb[(ni * 16 + l15) * 40 + quad * 8]);
#pragma unroll
    for (int ni = 0; ni < 5; ++ni)
      acc[ni] = __builtin_amdgcn_mfma_f32_16x16x32_bf16(af, bfr[ni], acc[ni], 0, 0, 0);
#pragma unroll
    for (int ni = 0; ni < 5; ++ni) {
      int col = ni * 16 + l15;
      float sc = scs[col];
#pragma unroll
      for (int r = 0; r < 4; ++r) {
        int row = wm + quad * 4 + r;
        float val = (sc > 0.0f) ? acc[ni][r] * rn[row] * sc : NEGBIG;
        unsigned pb = (__float_as_uint(val) & 0xFFFFFF80u) | (unsigned)col;
        S[row * SSTR + col] = __uint_as_float(pb);
      }
    }
  }
  __syncthreads();
  int allpad = allpad_s;
  // --- phase B: 4 threads/row, 20 elems each, packed top-5 + merge ---
  int row = qrow;                          // tid>>2
  const float* Srow = &S[row * SSTR];
  int t0 = qq * 20, t1 = (qq == 3) ? TT : t0 + 20;
  float tv0 = -INFINITY, tv1 = -INFINITY, tv2 = -INFINITY,
        tv3 = -INFINITY, tv4 = -INFINITY;
  for (int t = t0; t < t1; ++t)
    ins5(Srow[t], tv0, tv1, tv2, tv3, tv4);
#pragma unroll
  for (int m = 1; m <= 2; m <<= 1) {
    float n0 = __shfl_xor(tv0, m), n1 = __shfl_xor(tv1, m),
          n2 = __shfl_xor(tv2, m), n3 = __shfl_xor(tv3, m),
          n4 = __shfl_xor(tv4, m);
    ins5(n0, tv0, tv1, tv2, tv3, tv4);
    ins5(n1, tv0, tv1, tv2, tv3, tv4);
    ins5(n2, tv0, tv1, tv2, tv3, tv4);
    ins5(n3, tv0, tv1, tv2, tv3, tv4);
    ins5(n4, tv0, tv1, tv2, tv3, tv4);
  }
  float o[8];
#pragma unroll
  for (int d = 0; d < 8; ++d) o[d] = 0.f;
  if (!allpad) {
    float e0 = 1.0f;
    float e1 = expf(tv1 - tv0);
    float e2 = expf(tv2 - tv0);
    float e3 = expf(tv3 - tv0);
    float e4 = expf(tv4 - tv0);
    float inv = 1.0f / (e0 + e1 + e2 + e3 + e4);
    int i0 = __float_as_uint(tv0) & 0x7F, i1 = __float_as_uint(tv1) & 0x7F,
        i2 = __float_as_uint(tv2) & 0x7F, i3 = __float_as_uint(tv3) & 0x7F,
        i4 = __float_as_uint(tv4) & 0x7F;
    const float* v0p = &vs[i0 * VSTR + qq * 8];
    const float* v1p = &vs[i1 * VSTR + qq * 8];
    const float* v2p = &vs[i2 * VSTR + qq * 8];
    const float* v3p = &vs[i3 * VSTR + qq * 8];
    const float* v4p = &vs[i4 * VSTR + qq * 8];
#pragma unroll
    for (int d = 0; d < 8; ++d)
      o[d] = (e0 * v0p[d] + e1 * v1p[d] + e2 * v2p[d] + e3 * v3p[d] + e4 * v4p[d]) * inv;
  }
  unsigned short* qp = qa + qbase + (size_t)row * CV_ + qq * 8;
  uint4 ou;
  ou.x = ((unsigned)f2b(o[1]) << 16) | f2b(o[0]);
  ou.y = ((unsigned)f2b(o[3]) << 16) | f2b(o[2]);
  ou.z = ((unsigned)f2b(o[5]) << 16) | f2b(o[4]);
  ou.w = ((unsigned)f2b(o[7]) << 16) | f2b(o[6]);
  *reinterpret_cast<uint4*>(qp) = ou;
}

extern "C" void kernel_launch(void* const* d_in, const int* in_sizes, int n_in,
                              void* d_out, int out_size, void* d_ws, size_t ws_size,
                              hipStream_t stream) {
  const float* visual = (const float*)d_in[0];
  const float* text   = (const float*)d_in[1];
  const float* Wq  = (const float*)d_in[2];
  const float* bq  = (const float*)d_in[3];
  const float* Wk  = (const float*)d_in[4];
  const float* bk  = (const float*)d_in[5];
  const float* Wv  = (const float*)d_in[6];
  const float* bv  = (const float*)d_in[7];
  const float* Wo  = (const float*)d_in[8];
  const float* bo  = (const float*)d_in[9];
  const float* g1  = (const float*)d_in[10];
  const float* b1  = (const float*)d_in[11];
  const float* g2  = (const float*)d_in[12];
  const float* b2  = (const float*)d_in[13];
  const float* W1  = (const float*)d_in[14];
  const float* bf1 = (const float*)d_in[15];
  const float* W2  = (const float*)d_in[16];
  const float* bff2 = (const float*)d_in[17];
  const float* lsc = (const float*)d_in[18];
  const float* alp = (const float*)d_in[19];

  char* ws = (char*)d_ws;
  size_t off = 0;
  auto alloc = [&](size_t bytes) -> char* {
    char* p = ws + off;
    off += (bytes + 255) & ~(size_t)255;
    return p;
  };
  unsigned short* WqT = (unsigned short*)alloc((size_t)65536 * 2);
  unsigned short* WkT = (unsigned short*)alloc((size_t)131072 * 2);  // contiguous
  unsigned short* WvT = (unsigned short*)alloc((size_t)131072 * 2);  // with WkT
  unsigned short* WoT = (unsigned short*)alloc((size_t)65536 * 2);
  unsigned short* W1T = (unsigned short*)alloc((size_t)262144 * 2);
  unsigned short* W2T = (unsigned short*)alloc((size_t)262144 * 2);
  float*          bkv  = (float*)alloc(512 * 4);
  float*          kbuf = (float*)alloc((size_t)BT_ * CV_ * 4);
  float*          vbuf = (float*)alloc((size_t)BT_ * CV_ * 4);
  float*          padb = (float*)alloc((size_t)BT_ * 4);
  char* U = ws + off;
  unsigned short* xbuf = (unsigned short*)U;
  unsigned short* qbuf = (unsigned short*)(U + 16777216);
  unsigned short* hbuf = (unsigned short*)(U + 16777216);
  float*          ybuf = (float*)d_out;
  bool fullFFN = (ws_size >= off + (size_t)16777216 + (size_t)67108864);

  // 1. prep: LN1 + weight convT + kv bias + pad mask
  prep_kernel<<<11932, 256, 0, stream>>>(visual, g1, b1, xbuf,
                                         Wq, Wk, Wv, Wo, W1, W2,
                                         WqT, WkT, WvT, WoT, W1T, W2T,
                                         bk, bv, bkv, text, padb);
  // 2. q = x @ Wq + bq  (bf16)
  gemm_fast<128><<<dim3(256, 2), 256, 0, stream>>>(
      xbuf, WqT, bq, nullptr, nullptr, qbuf, MROW, 256, 256, 0);
  // 3. k|v = text @ [WkT;WvT]^T + bkv  (fp32 split outputs)
  gemm_kv<<<dim3(10, 8), 256, 0, stream>>>(text, WkT, bkv, kbuf, vbuf);
  // 4. attention v3: qbuf -> qbuf in place
  attn_kernel<<<dim3(64, NH_, NB), 256, 0, stream>>>(qbuf, kbuf, vbuf, padb, lsc);
  // 5. fused o-proj + residual + LN2: y bf16 (xbuf) + y fp32 (d_out)
  gemm_oln<<<256, 256, 0, stream>>>(qbuf, WoT, bo, xbuf, alp, g2, b2,
                                    xbuf, ybuf);
  // 6+7. FFN
  if (fullFFN) {
    gemm_fast<128><<<dim3(256, 8), 256, 0, stream>>>(
        xbuf, W1T, bf1, nullptr, nullptr, hbuf, MROW, 1024, 256, 2);
    gemm_fast<64><<<dim3(256, 4), 256, 0, stream>>>(
        hbuf, W2T, bff2, ybuf, nullptr, (void*)ybuf, MROW, 256, 1024, 1 | 8);
  } else {
    for (int half = 0; half < 2; ++half) {
      const unsigned short* xh = xbuf + (size_t)half * 16384 * CV_;
      const float* yh = ybuf + (size_t)half * 16384 * CV_;
      gemm_fast<128><<<dim3(128, 8), 256, 0, stream>>>(
          xh, W1T, bf1, nullptr, nullptr, hbuf, 16384, 1024, 256, 2);
      gemm_fast<64><<<dim3(128, 4), 256, 0, stream>>>(
          hbuf, W2T, bff2, yh, nullptr, (void*)yh, 16384, 256, 1024, 1 | 8);
    }
  }
}

// Round 9
// 307.821 us; speedup vs baseline: 1.1417x; 1.0762x over previous
//
#include <hip/hip_runtime.h>
#include <math.h>

// Problem constants
#define NB   8
#define NPIX 4096          // H*W
#define MROW 32768         // B*H*W
#define CV_  256
#define TT   77
#define CT_  512
#define NH_  8
#define DH_  32
#define BT_  616           // B*T

typedef __bf16 bf16x8 __attribute__((ext_vector_type(8)));
typedef float  f32x4  __attribute__((ext_vector_type(4)));

__device__ __forceinline__ float bf2f(unsigned short u) {
  return __uint_as_float(((unsigned)u) << 16);
}
__device__ __forceinline__ unsigned short f2b(float f) {
  unsigned u = __float_as_uint(f);
  return (unsigned short)((u + 0x7FFFu + ((u >> 16) & 1u)) >> 16);
}
__device__ __forceinline__ unsigned pack2(float lo, float hi) {
  return ((unsigned)f2b(hi) << 16) | (unsigned)f2b(lo);
}
__device__ __forceinline__ void async_copy16(const unsigned short* g,
                                             unsigned short* l) {
  __builtin_amdgcn_global_load_lds(
      (const __attribute__((address_space(1))) void*)g,
      (__attribute__((address_space(3))) void*)l, 16, 0, 0);
}
// tanh-GELU: 0.5*v*(1+tanh(0.79788456*(v+0.044715 v^3))) = v - v/(e^{2u}+1)
__device__ __forceinline__ float gelu_t(float v) {
  float p = v * fmaf(0.0713548162726f, v * v, 1.59576912161f);
  float e = __expf(p);
  return v - v / (e + 1.0f);
}

// -- prep: LN1 (0..8191) + weight convT + kv bias (..11777) + pad (..11931) --
__global__ __launch_bounds__(256) void prep_kernel(
    const float* __restrict__ visual, const float* __restrict__ g1,
    const float* __restrict__ b1, unsigned short* __restrict__ xbuf,
    const float* __restrict__ s0, const float* __restrict__ s1,
    const float* __restrict__ s2, const float* __restrict__ s3,
    const float* __restrict__ s4, const float* __restrict__ s5,
    unsigned short* __restrict__ d0, unsigned short* __restrict__ d1,
    unsigned short* __restrict__ d2, unsigned short* __restrict__ d3,
    unsigned short* __restrict__ d4, unsigned short* __restrict__ d5,
    const float* __restrict__ bk, const float* __restrict__ bv,
    float* __restrict__ bkv, const float* __restrict__ text,
    float* __restrict__ padb) {
  int bx = blockIdx.x;
  int wave = threadIdx.x >> 6, lane = threadIdx.x & 63;
  if (bx < 8192) {                       // LN1: visual fp32 -> x bf16
    int row = bx * 4 + wave;
    size_t base = (size_t)row * 256 + lane * 4;
    float4 f = *reinterpret_cast<const float4*>(visual + base);
    float v0 = f.x, v1 = f.y, v2 = f.z, v3 = f.w;
    float s = v0 + v1 + v2 + v3;
    float q = v0 * v0 + v1 * v1 + v2 * v2 + v3 * v3;
#pragma unroll
    for (int off = 1; off < 64; off <<= 1) {
      s += __shfl_xor(s, off);
      q += __shfl_xor(q, off);
    }
    float mean = s * (1.0f / 256.0f);
    float var  = q * (1.0f / 256.0f) - mean * mean;
    float rstd = rsqrtf(var + 1e-5f);
    float4 gv = *reinterpret_cast<const float4*>(g1 + lane * 4);
    float4 bv4 = *reinterpret_cast<const float4*>(b1 + lane * 4);
    ushort4 o;
    o.x = f2b((v0 - mean) * rstd * gv.x + bv4.x);
    o.y = f2b((v1 - mean) * rstd * gv.y + bv4.y);
    o.z = f2b((v2 - mean) * rstd * gv.z + bv4.z);
    o.w = f2b((v3 - mean) * rstd * gv.w + bv4.w);
    *reinterpret_cast<ushort4*>(xbuf + base) = o;
    return;
  }
  if (bx >= 11778) {                     // pad mask: one wave per (b,t) row
    int row = (bx - 11778) * 4 + wave;   // 0..615
    const float* tr = text + (size_t)row * CT_ + lane * 8;
    float4 f0 = *reinterpret_cast<const float4*>(tr);
    float4 f1 = *reinterpret_cast<const float4*>(tr + 4);
    float s = fabsf(f0.x) + fabsf(f0.y) + fabsf(f0.z) + fabsf(f0.w)
            + fabsf(f1.x) + fabsf(f1.y) + fabsf(f1.z) + fabsf(f1.w);
#pragma unroll
    for (int off = 1; off < 64; off <<= 1) s += __shfl_xor(s, off);
    if (lane == 0) padb[row] = (s <= 1e-6f) ? 1.0f : 0.0f;
    return;
  }
  int gi = (bx - 8192) * 256 + threadIdx.x;
  const float* src; unsigned short* dst; int R, C, idx;
  if      (gi < 65536)  { src=s0; dst=d0; R=256;  C=256;  idx=gi; }
  else if (gi < 196608) { src=s1; dst=d1; R=512;  C=256;  idx=gi-65536; }
  else if (gi < 327680) { src=s2; dst=d2; R=512;  C=256;  idx=gi-196608; }
  else if (gi < 393216) { src=s3; dst=d3; R=256;  C=256;  idx=gi-327680; }
  else if (gi < 655360) { src=s4; dst=d4; R=256;  C=1024; idx=gi-393216; }
  else if (gi < 917504) { src=s5; dst=d5; R=1024; C=256;  idx=gi-655360; }
  else if (gi < 918016) {
    int i = gi - 917504;
    bkv[i] = (i < 256) ? bk[i] : bv[i - 256];
    return;
  } else return;
  int r = idx / C, c = idx - r * C;
  dst[(size_t)c * R + r] = f2b(src[idx]);
}

// ---- merged q-proj (blocks 0..511) + kv GEMM (blocks 512..591) ----------
__global__ __launch_bounds__(256) void qkv_kernel(
    const unsigned short* __restrict__ xb, const unsigned short* __restrict__ WqT,
    const float* __restrict__ bq, unsigned short* __restrict__ qout,
    const float* __restrict__ text, const unsigned short* __restrict__ WkvT,
    const float* __restrict__ bkv, float* __restrict__ kout,
    float* __restrict__ vout) {
  __shared__ unsigned short lA[4096];
  __shared__ unsigned short lB[4096];
  int tid = threadIdx.x;
  int lane = tid & 63, wave = tid >> 6;
  int l15 = lane & 15, quad = lane >> 4;
  if (blockIdx.x < 512) {
    // ---- q-proj: 128x128 tile, K=256, m97 async staging ----
    int bm = (blockIdx.x >> 1) * 128, bn = (blockIdx.x & 1) * 128;
    int wm = (wave & 1) * 64, wn = (wave >> 1) * 64;
    int crow = lane >> 2, ccol = (lane & 3) * 8;
    f32x4 acc[4][4] = {};
    for (int k0 = 0; k0 < 256; k0 += 32) {
#pragma unroll
      for (int ch = 0; ch < 2; ++ch) {
        int c = wave * 2 + ch;
        async_copy16(xb + (size_t)(bm + c * 16 + crow) * 256 + k0 + ccol,
                     &lA[c * 512]);
        async_copy16(WqT + (size_t)(bn + c * 16 + crow) * 256 + k0 + ccol,
                     &lB[c * 512]);
      }
      __syncthreads();
      bf16x8 af[4], bfr[4];
#pragma unroll
      for (int mi = 0; mi < 4; ++mi)
        af[mi] = *reinterpret_cast<const bf16x8*>(&lA[(wm + mi * 16 + l15) * 32 + quad * 8]);
#pragma unroll
      for (int ni = 0; ni < 4; ++ni)
        bfr[ni] = *reinterpret_cast<const bf16x8*>(&lB[(wn + ni * 16 + l15) * 32 + quad * 8]);
#pragma unroll
      for (int mi = 0; mi < 4; ++mi)
#pragma unroll
        for (int ni = 0; ni < 4; ++ni)
          acc[mi][ni] = __builtin_amdgcn_mfma_f32_16x16x32_bf16(af[mi], bfr[ni],
                                                                acc[mi][ni], 0, 0, 0);
      __syncthreads();
    }
#pragma unroll
    for (int mi = 0; mi < 4; ++mi) {
#pragma unroll
      for (int ni = 0; ni < 4; ++ni) {
        int gcol = bn + wn + ni * 16 + l15;
        float bsf = bq[gcol];
#pragma unroll
        for (int r = 0; r < 4; ++r) {
          int grow = bm + wm + mi * 16 + quad * 4 + r;
          qout[(size_t)grow * 256 + gcol] = f2b(acc[mi][ni][r] + bsf);
        }
      }
    }
  } else {
    // ---- kv: 64x64 tile over (616, 512), K=512, fp32 A pack ----
    int i = blockIdx.x - 512;
    int bm = (i % 10) * 64, bn = (i / 10) * 64;
    int srow = tid >> 2, sc8 = (tid & 3) * 8;
    int wm = (wave & 1) * 32, wn = (wave >> 1) * 32;
    f32x4 acc[2][2] = {};
    int gm = bm + srow, gn = bn + srow;
    const bool aok = (gm < BT_);
    for (int k0 = 0; k0 < CT_; k0 += 32) {
      uint4 apk = make_uint4(0, 0, 0, 0);
      if (aok) {
        const float* Af = text + (size_t)gm * CT_ + k0 + sc8;
        float4 f0 = *reinterpret_cast<const float4*>(Af);
        float4 f1 = *reinterpret_cast<const float4*>(Af + 4);
        apk.x = pack2(f0.x, f0.y); apk.y = pack2(f0.z, f0.w);
        apk.z = pack2(f1.x, f1.y); apk.w = pack2(f1.z, f1.w);
      }
      uint4 bpk = *reinterpret_cast<const uint4*>(WkvT + (size_t)gn * CT_ + k0 + sc8);
      *reinterpret_cast<uint4*>(&lA[srow * 40 + sc8]) = apk;
      *reinterpret_cast<uint4*>(&lB[srow * 40 + sc8]) = bpk;
      __syncthreads();
      bf16x8 a0 = *reinterpret_cast<const bf16x8*>(&lA[(wm + l15) * 40 + quad * 8]);
      bf16x8 a1 = *reinterpret_cast<const bf16x8*>(&lA[(wm + 16 + l15) * 40 + quad * 8]);
      bf16x8 b0 = *reinterpret_cast<const bf16x8*>(&lB[(wn + l15) * 40 + quad * 8]);
      bf16x8 b1 = *reinterpret_cast<const bf16x8*>(&lB[(wn + 16 + l15) * 40 + quad * 8]);
      acc[0][0] = __builtin_amdgcn_mfma_f32_16x16x32_bf16(a0, b0, acc[0][0], 0, 0, 0);
      acc[0][1] = __builtin_amdgcn_mfma_f32_16x16x32_bf16(a0, b1, acc[0][1], 0, 0, 0);
      acc[1][0] = __builtin_amdgcn_mfma_f32_16x16x32_bf16(a1, b0, acc[1][0], 0, 0, 0);
      acc[1][1] = __builtin_amdgcn_mfma_f32_16x16x32_bf16(a1, b1, acc[1][1], 0, 0, 0);
      __syncthreads();
    }
#pragma unroll
    for (int mt = 0; mt < 2; ++mt) {
#pragma unroll
      for (int nt = 0; nt < 2; ++nt) {
        int gcol = bn + wn + nt * 16 + l15;
        float bsf = bkv[gcol];
#pragma unroll
        for (int r = 0; r < 4; ++r) {
          int grow = bm + wm + mt * 16 + quad * 4 + r;
          if (grow >= BT_) continue;
          float v = acc[mt][nt][r] + bsf;
          if (gcol < 256) kout[(size_t)grow * 256 + gcol] = v;
          else            vout[(size_t)grow * 256 + gcol - 256] = v;
        }
      }
    }
  }
}

// ---- fused o-proj + residual + LN2 (128 rows/block, full rows) ----------
__global__ __launch_bounds__(256) void gemm_oln(
    const unsigned short* __restrict__ A, const unsigned short* __restrict__ Bt,
    const float* __restrict__ bias, const unsigned short* __restrict__ xres,
    const float* __restrict__ alpha_ptr,
    const float* __restrict__ g2, const float* __restrict__ b2,
    unsigned short* __restrict__ ybf, float* __restrict__ yf32) {
  __shared__ unsigned short sm[32768];
  unsigned short* lA = sm;
  unsigned short* lB = sm + 4096;
  unsigned short* yt = sm;
  const int K = 256;
  int tid = threadIdx.x;
  int bm = blockIdx.x * 128;
  int lane = tid & 63, wave = tid >> 6;
  int wm = (wave & 1) * 64, wn = (wave >> 1) * 128;
  int l15 = lane & 15, quad = lane >> 4;
  int crow = lane >> 2, ccol = (lane & 3) * 8;
  f32x4 acc[4][8] = {};
  for (int k0 = 0; k0 < K; k0 += 32) {
#pragma unroll
    for (int ch = 0; ch < 2; ++ch) {
      int c = wave * 2 + ch;
      async_copy16(A + (size_t)(bm + c * 16 + crow) * K + k0 + ccol,
                   &lA[c * 512]);
    }
#pragma unroll
    for (int ch = wave; ch < 16; ch += 4)
      async_copy16(Bt + (size_t)(ch * 16 + crow) * K + k0 + ccol,
                   &lB[ch * 512]);
    __syncthreads();
    bf16x8 af[4], bfr[8];
#pragma unroll
    for (int mi = 0; mi < 4; ++mi)
      af[mi] = *reinterpret_cast<const bf16x8*>(&lA[(wm + mi * 16 + l15) * 32 + quad * 8]);
#pragma unroll
    for (int ni = 0; ni < 8; ++ni)
      bfr[ni] = *reinterpret_cast<const bf16x8*>(&lB[(wn + ni * 16 + l15) * 32 + quad * 8]);
#pragma unroll
    for (int mi = 0; mi < 4; ++mi)
#pragma unroll
      for (int ni = 0; ni < 8; ++ni)
        acc[mi][ni] = __builtin_amdgcn_mfma_f32_16x16x32_bf16(af[mi], bfr[ni],
                                                              acc[mi][ni], 0, 0, 0);
    __syncthreads();
  }
  float alpha = *alpha_ptr;
#pragma unroll
  for (int mi = 0; mi < 4; ++mi) {
#pragma unroll
    for (int ni = 0; ni < 8; ++ni) {
      int gcol = wn + ni * 16 + l15;
      float bsf = bias[gcol];
#pragma unroll
      for (int r = 0; r < 4; ++r) {
        int lrow = wm + mi * 16 + quad * 4 + r;
        float v = acc[mi][ni][r] + bsf;
        float y0 = bf2f(xres[(size_t)(bm + lrow) * 256 + gcol]) + alpha * v;
        yt[lrow * 256 + gcol] = f2b(y0);
      }
    }
  }
  __syncthreads();
  for (int it = 0; it < 32; ++it) {
    int row = wave * 32 + it;
    ushort4 u = *reinterpret_cast<const ushort4*>(&yt[row * 256 + lane * 4]);
    float v0 = bf2f(u.x), v1 = bf2f(u.y), v2 = bf2f(u.z), v3 = bf2f(u.w);
    float s = v0 + v1 + v2 + v3;
    float q = v0 * v0 + v1 * v1 + v2 * v2 + v3 * v3;
#pragma unroll
    for (int off = 1; off < 64; off <<= 1) {
      s += __shfl_xor(s, off);
      q += __shfl_xor(q, off);
    }
    float mean = s * (1.0f / 256.0f);
    float var  = q * (1.0f / 256.0f) - mean * mean;
    float rstd = rsqrtf(var + 1e-5f);
    float4 gv = *reinterpret_cast<const float4*>(g2 + lane * 4);
    float4 bv = *reinterpret_cast<const float4*>(b2 + lane * 4);
    float o0 = (v0 - mean) * rstd * gv.x + bv.x;
    float o1 = (v1 - mean) * rstd * gv.y + bv.y;
    float o2 = (v2 - mean) * rstd * gv.z + bv.z;
    float o3 = (v3 - mean) * rstd * gv.w + bv.w;
    size_t base = (size_t)(bm + row) * 256 + lane * 4;
    ushort4 ob;
    ob.x = f2b(o0); ob.y = f2b(o1); ob.z = f2b(o2); ob.w = f2b(o3);
    *reinterpret_cast<ushort4*>(ybf + base) = ob;
    *reinterpret_cast<float4*>(yf32 + base) = make_float4(o0, o1, o2, o3);
  }
}

// ---------- attention v3: MFMA QK^T + packed-index top-5 ------------------
#define SSTR 83
#define VSTR 33
#define NEGBIG -3.0e38f
__device__ __forceinline__ void ins5(float sv, float& tv0, float& tv1,
                                     float& tv2, float& tv3, float& tv4) {
  bool g0 = sv > tv0, g1 = sv > tv1, g2 = sv > tv2, g3 = sv > tv3, g4 = sv > tv4;
  tv4 = g4 ? (g3 ? tv3 : sv) : tv4;
  tv3 = g3 ? (g2 ? tv2 : sv) : tv3;
  tv2 = g2 ? (g1 ? tv1 : sv) : tv2;
  tv1 = g1 ? (g0 ? tv0 : sv) : tv1;
  tv0 = g0 ? sv : tv0;
}
__global__ __launch_bounds__(256) void attn_kernel(
    unsigned short* qa, const float* __restrict__ k,
    const float* __restrict__ v, const float* __restrict__ padb,
    const float* __restrict__ ls_ptr) {
  __shared__ unsigned short qb[64 * 40];
  __shared__ unsigned short kb[80 * 40];
  __shared__ float S[64 * SSTR];
  __shared__ float vs[TT * VSTR];
  __shared__ float rn[64];
  __shared__ float scs[80];
  __shared__ int allpad_s;
  int tid = threadIdx.x;
  int h = blockIdx.y, b = blockIdx.z;
  size_t qbase = ((size_t)b * NPIX + blockIdx.x * 64) * CV_ + h * DH_;
  size_t kvbase = (size_t)b * TT * CV_ + h * DH_;
  float ls = *ls_ptr;
  ls = fminf(fmaxf(ls, -2.0f), 2.0f);
  float scale = expf(ls) * 0.17677669529663687f;
  if (tid == 0) allpad_s = 1;
  __syncthreads();
  int qrow = tid >> 2, qq = tid & 3;
  uint4 qv4 = *reinterpret_cast<const uint4*>(qa + qbase + (size_t)qrow * CV_ + qq * 8);
  *reinterpret_cast<uint4*>(&qb[qrow * 40 + qq * 8]) = qv4;
  {
    float ssq = 0.f;
    unsigned w[4] = {qv4.x, qv4.y, qv4.z, qv4.w};
#pragma unroll
    for (int i = 0; i < 4; ++i) {
      float a = bf2f((unsigned short)(w[i] & 0xFFFF));
      float bb = bf2f((unsigned short)(w[i] >> 16));
      ssq += a * a + bb * bb;
    }
    ssq += __shfl_xor(ssq, 1);
    ssq += __shfl_xor(ssq, 2);
    if (qq == 0) rn[qrow] = scale / fmaxf(sqrtf(ssq), 1e-6f);
  }
  if (tid < 154) {
    int kr = tid >> 1, kh = tid & 1;
    const float* kp = k + kvbase + (size_t)kr * CV_ + kh * 16;
    float4 f0 = *reinterpret_cast<const float4*>(kp);
    float4 f1 = *reinterpret_cast<const float4*>(kp + 4);
    float4 f2 = *reinterpret_cast<const float4*>(kp + 8);
    float4 f3 = *reinterpret_cast<const float4*>(kp + 12);
    float ks2 = f0.x*f0.x + f0.y*f0.y + f0.z*f0.z + f0.w*f0.w
              + f1.x*f1.x + f1.y*f1.y + f1.z*f1.z + f1.w*f1.w
              + f2.x*f2.x + f2.y*f2.y + f2.z*f2.z + f2.w*f2.w
              + f3.x*f3.x + f3.y*f3.y + f3.z*f3.z + f3.w*f3.w;
    uint4 p0, p1;
    p0.x = pack2(f0.x, f0.y); p0.y = pack2(f0.z, f0.w);
    p0.z = pack2(f1.x, f1.y); p0.w = pack2(f1.z, f1.w);
    p1.x = pack2(f2.x, f2.y); p1.y = pack2(f2.z, f2.w);
    p1.z = pack2(f3.x, f3.y); p1.w = pack2(f3.z, f3.w);
    *reinterpret_cast<uint4*>(&kb[kr * 40 + kh * 16]) = p0;
    *reinterpret_cast<uint4*>(&kb[kr * 40 + kh * 16 + 8]) = p1;
    ks2 += __shfl_xor(ks2, 1);
    if (kh == 0) {
      float p = padb[b * TT + kr];
      float sc = (p == 0.0f) ? 1.0f / fmaxf(sqrtf(ks2), 1e-6f) : 0.0f;
      scs[kr] = sc;
      if (sc > 0.0f) allpad_s = 0;
    }
  } else if (tid < 157) {
    scs[77 + (tid - 154)] = 0.0f;
  } else if (tid >= 160 && tid < 172) {
    int i = tid - 160;
    *reinterpret_cast<uint4*>(&kb[(77 + (i >> 2)) * 40 + (i & 3) * 8]) =
        make_uint4(0, 0, 0, 0);
  }
  for (int j = tid; j < TT * 8; j += 256) {
    int t = j >> 3, d4 = j & 7;
    float4 f = *reinterpret_cast<const float4*>(
        v + kvbase + (size_t)t * CV_ + d4 * 4);
    float* vp = &vs[t * VSTR + d4 * 4];
    vp[0] = f.x; vp[1] = f.y; vp[2] = f.z; vp[3] = f.w;
  }
  __syncthreads();
  {
    int lane = tid & 63, wave = tid >> 6;
    int wm = wave * 16;
    int l15 = lane & 15, quad = lane >> 4;
    f32x4 acc[5] = {};
    bf16x8 af = *reinterpret_cast<const bf16x8*>(&qb[(wm + l15) * 40 + quad * 8]);
    bf16x8 bfr[5];
#pragma unroll
    for (int ni = 0; ni < 5; ++ni)
      bfr[ni] = *reinterpret_cast<const bf16x8*>(&kb[(ni * 16 + l15) * 40 + quad * 8]);
#pragma unroll
    for (int ni = 0; ni < 5; ++ni)
      acc[ni] = __builtin_amdgcn_mfma_f32_16x16x32_bf16(af, bfr[ni], acc[ni], 0, 0, 0);
#pragma unroll
    for (int ni = 0; ni < 5; ++ni) {
      int col = ni * 16 + l15;
      float sc = scs[col];
#pragma unroll
      for (int r = 0; r < 4; ++r) {
        int row = wm + quad * 4 + r;
        float val = (sc > 0.0f) ? acc[ni][r] * rn[row] * sc : NEGBIG;
        unsigned pb = (__float_as_uint(val) & 0xFFFFFF80u) | (unsigned)col;
        S[row * SSTR + col] = __uint_as_float(pb);
      }
    }
  }
  __syncthreads();
  int allpad = allpad_s;
  int row = qrow;
  const float* Srow = &S[row * SSTR];
  int t0 = qq * 20, t1 = (qq == 3) ? TT : t0 + 20;
  float tv0 = -INFINITY, tv1 = -INFINITY, tv2 = -INFINITY,
        tv3 = -INFINITY, tv4 = -INFINITY;
  for (int t = t0; t < t1; ++t)
    ins5(Srow[t], tv0, tv1, tv2, tv3, tv4);
#pragma unroll
  for (int m = 1; m <= 2; m <<= 1) {
    float n0 = __shfl_xor(tv0, m), n1 = __shfl_xor(tv1, m),
          n2 = __shfl_xor(tv2, m), n3 = __shfl_xor(tv3, m),
          n4 = __shfl_xor(tv4, m);
    ins5(n0, tv0, tv1, tv2, tv3, tv4);
    ins5(n1, tv0, tv1, tv2, tv3, tv4);
    ins5(n2, tv0, tv1, tv2, tv3, tv4);
    ins5(n3, tv0, tv1, tv2, tv3, tv4);
    ins5(n4, tv0, tv1, tv2, tv3, tv4);
  }
  float o[8];
#pragma unroll
  for (int d = 0; d < 8; ++d) o[d] = 0.f;
  if (!allpad) {
    float e0 = 1.0f;
    float e1 = expf(tv1 - tv0);
    float e2 = expf(tv2 - tv0);
    float e3 = expf(tv3 - tv0);
    float e4 = expf(tv4 - tv0);
    float inv = 1.0f / (e0 + e1 + e2 + e3 + e4);
    int i0 = __float_as_uint(tv0) & 0x7F, i1 = __float_as_uint(tv1) & 0x7F,
        i2 = __float_as_uint(tv2) & 0x7F, i3 = __float_as_uint(tv3) & 0x7F,
        i4 = __float_as_uint(tv4) & 0x7F;
    const float* v0p = &vs[i0 * VSTR + qq * 8];
    const float* v1p = &vs[i1 * VSTR + qq * 8];
    const float* v2p = &vs[i2 * VSTR + qq * 8];
    const float* v3p = &vs[i3 * VSTR + qq * 8];
    const float* v4p = &vs[i4 * VSTR + qq * 8];
#pragma unroll
    for (int d = 0; d < 8; ++d)
      o[d] = (e0 * v0p[d] + e1 * v1p[d] + e2 * v2p[d] + e3 * v3p[d] + e4 * v4p[d]) * inv;
  }
  unsigned short* qp = qa + qbase + (size_t)row * CV_ + qq * 8;
  uint4 ou;
  ou.x = ((unsigned)f2b(o[1]) << 16) | f2b(o[0]);
  ou.y = ((unsigned)f2b(o[3]) << 16) | f2b(o[2]);
  ou.z = ((unsigned)f2b(o[5]) << 16) | f2b(o[4]);
  ou.w = ((unsigned)f2b(o[7]) << 16) | f2b(o[6]);
  *reinterpret_cast<uint4*>(qp) = ou;
}

// ---------- fused FFN: out = y + gelu(y@W1+b1)@W2 + b2 -------------------
// 256 blocks (1/CU), 128 rows each. y-tile LDS-resident; 8 hidden chunks:
// phase1 H = gelu(W1c @ y^T) (A=W1 -> lane accs hid-consecutive -> b64 writes)
// phase2 acc += H @ W2c^T (persistent 128-reg accumulator). No hdn in HBM.
#define XSTR 264   // y-tile stride (2-way-free A/B reads)
#define HSTR 136   // H stride
__global__ __launch_bounds__(256, 1) void ffn_fused(
    const unsigned short* __restrict__ ybf, const unsigned short* __restrict__ W1T,
    const float* __restrict__ b1f, const unsigned short* __restrict__ W2T,
    const float* __restrict__ b2f, float* __restrict__ yio) {
  __shared__ unsigned short xs[128 * XSTR];  // 67584 B
  __shared__ unsigned short Hs[128 * HSTR];  // 34816 B
  __shared__ unsigned short Wb[16384];       // 32 KB
  int tid = threadIdx.x, lane = tid & 63, wave = tid >> 6;
  int l15 = lane & 15, quad = lane >> 4;
  int crow = lane >> 2, ccol = (lane & 3) * 8;
  int bm = blockIdx.x * 128;
  {  // stage y-tile (padded stride -> VGPR path)
    int row = tid >> 1, kh = (tid & 1) * 128;
    const unsigned short* src = ybf + (size_t)(bm + row) * 256 + kh;
    unsigned short* dst = &xs[row * XSTR + kh];
#pragma unroll
    for (int i = 0; i < 16; ++i)
      *reinterpret_cast<uint4*>(dst + i * 8) =
          *reinterpret_cast<const uint4*>(src + i * 8);
  }
  int wm2 = (wave & 1) * 64, wn2 = (wave >> 1) * 128;  // phase2 tile
  int wh1 = (wave & 1) * 64, wr1 = (wave >> 1) * 64;   // phase1 tile
  f32x4 acc[4][8] = {};
  for (int c = 0; c < 8; ++c) {
    f32x4 acc1[4][4] = {};
    // ---- phase 1: D(hid,row) = W1chunk @ y^T, K=256 in 2 slabs ----
    for (int slab = 0; slab < 2; ++slab) {
      int k0 = slab * 128;
      __syncthreads();
#pragma unroll
      for (int s = 0; s < 4; ++s)
#pragma unroll
        for (int i = 0; i < 2; ++i) {
          int ch = wave * 2 + i;
          async_copy16(W1T + (size_t)(c * 128 + ch * 16 + crow) * 256
                           + k0 + s * 32 + ccol,
                       &Wb[s * 4096 + ch * 512]);
        }
      __syncthreads();
#pragma unroll
      for (int s = 0; s < 4; ++s) {
        bf16x8 af[4], bfr[4];
#pragma unroll
        for (int mi = 0; mi < 4; ++mi)
          af[mi] = *reinterpret_cast<const bf16x8*>(
              &Wb[s * 4096 + (wh1 + mi * 16 + l15) * 32 + quad * 8]);
#pragma unroll
        for (int ni = 0; ni < 4; ++ni)
          bfr[ni] = *reinterpret_cast<const bf16x8*>(
              &xs[(wr1 + ni * 16 + l15) * XSTR + k0 + s * 32 + quad * 8]);
#pragma unroll
        for (int mi = 0; mi < 4; ++mi)
#pragma unroll
          for (int ni = 0; ni < 4; ++ni)
            acc1[mi][ni] = __builtin_amdgcn_mfma_f32_16x16x32_bf16(
                af[mi], bfr[ni], acc1[mi][ni], 0, 0, 0);
      }
    }
    // ---- GELU + bias, write H (b64: 4 hid-consecutive per lane) ----
#pragma unroll
    for (int mi = 0; mi < 4; ++mi) {
      int hb = wh1 + mi * 16 + quad * 4;
      float b0 = b1f[c * 128 + hb],     b1v = b1f[c * 128 + hb + 1];
      float b2v = b1f[c * 128 + hb + 2], b3 = b1f[c * 128 + hb + 3];
#pragma unroll
      for (int ni = 0; ni < 4; ++ni) {
        int row = wr1 + ni * 16 + l15;
        ushort4 hw;
        hw.x = f2b(gelu_t(acc1[mi][ni][0] + b0));
        hw.y = f2b(gelu_t(acc1[mi][ni][1] + b1v));
        hw.z = f2b(gelu_t(acc1[mi][ni][2] + b2v));
        hw.w = f2b(gelu_t(acc1[mi][ni][3] + b3));
        *reinterpret_cast<ushort4*>(&Hs[row * HSTR + hb]) = hw;
      }
    }
    // ---- phase 2: acc += H @ W2chunk^T (K=128 in 2 stages of 64) ----
#pragma unroll
    for (int j = 0; j < 2; ++j) {
      __syncthreads();   // H visible (j=0) + Wb reads of prior stage done
#pragma unroll
      for (int u = 0; u < 2; ++u)
#pragma unroll
        for (int i = 0; i < 4; ++i) {
          int ch = wave * 4 + i;   // 16 chunks of 16 rows (256 rows)
          async_copy16(W2T + (size_t)(ch * 16 + crow) * 1024
                           + c * 128 + j * 64 + u * 32 + ccol,
                       &Wb[u * 8192 + ch * 512]);
        }
      __syncthreads();
#pragma unroll
      for (int u = 0; u < 2; ++u) {
        int kk = j * 64 + u * 32;
        bf16x8 af[4], bfr[8];
#pragma unroll
        for (int mi = 0; mi < 4; ++mi)
          af[mi] = *reinterpret_cast<const bf16x8*>(
              &Hs[(wm2 + mi * 16 + l15) * HSTR + kk + quad * 8]);
#pragma unroll
        for (int ni = 0; ni < 8; ++ni)
          bfr[ni] = *reinterpret_cast<const bf16x8*>(
              &Wb[u * 8192 + (wn2 + ni * 16 + l15) * 32 + quad * 8]);
#pragma unroll
        for (int mi = 0; mi < 4; ++mi)
#pragma unroll
          for (int ni = 0; ni < 8; ++ni)
            acc[mi][ni] = __builtin_amdgcn_mfma_f32_16x16x32_bf16(
                af[mi], bfr[ni], acc[mi][ni], 0, 0, 0);
      }
    }
  }
  // ---- epilogue: out = resid + acc + b2 (fp32 RMW, thread-owned) ----
#pragma unroll
  for (int mi = 0; mi < 4; ++mi)
#pragma unroll
    for (int ni = 0; ni < 8; ++ni) {
      int col = wn2 + ni * 16 + l15;
      float bs = b2f[col];
#pragma unroll
      for (int r = 0; r < 4; ++r) {
        int g = bm + wm2 + mi * 16 + quad * 4 + r;
        size_t oi = (size_t)g * 256 + col;
        yio[oi] = yio[oi] + acc[mi][ni][r] + bs;
      }
    }
}

extern "C" void kernel_launch(void* const* d_in, const int* in_sizes, int n_in,
                              void* d_out, int out_size, void* d_ws, size_t ws_size,
                              hipStream_t stream) {
  const float* visual = (const float*)d_in[0];
  const float* text   = (const float*)d_in[1];
  const float* Wq  = (const float*)d_in[2];
  const float* bq  = (const float*)d_in[3];
  const float* Wk  = (const float*)d_in[4];
  const float* bk  = (const float*)d_in[5];
  const float* Wv  = (const float*)d_in[6];
  const float* bv  = (const float*)d_in[7];
  const float* Wo  = (const float*)d_in[8];
  const float* bo  = (const float*)d_in[9];
  const float* g1  = (const float*)d_in[10];
  const float* b1  = (const float*)d_in[11];
  const float* g2  = (const float*)d_in[12];
  const float* b2  = (const float*)d_in[13];
  const float* W1  = (const float*)d_in[14];
  const float* bf1 = (const float*)d_in[15];
  const float* W2  = (const float*)d_in[16];
  const float* bff2 = (const float*)d_in[17];
  const float* lsc = (const float*)d_in[18];
  const float* alp = (const float*)d_in[19];

  char* ws = (char*)d_ws;
  size_t off = 0;
  auto alloc = [&](size_t bytes) -> char* {
    char* p = ws + off;
    off += (bytes + 255) & ~(size_t)255;
    return p;
  };
  unsigned short* WqT = (unsigned short*)alloc((size_t)65536 * 2);
  unsigned short* WkT = (unsigned short*)alloc((size_t)131072 * 2);  // contiguous
  unsigned short* WvT = (unsigned short*)alloc((size_t)131072 * 2);  // with WkT
  unsigned short* WoT = (unsigned short*)alloc((size_t)65536 * 2);
  unsigned short* W1T = (unsigned short*)alloc((size_t)262144 * 2);
  unsigned short* W2T = (unsigned short*)alloc((size_t)262144 * 2);
  float*          bkv  = (float*)alloc(512 * 4);
  float*          kbuf = (float*)alloc((size_t)BT_ * CV_ * 4);
  float*          vbuf = (float*)alloc((size_t)BT_ * CV_ * 4);
  float*          padb = (float*)alloc((size_t)BT_ * 4);
  char* U = ws + off;                      // total ws ~= 36.3 MB
  unsigned short* xbuf = (unsigned short*)U;
  unsigned short* qbuf = (unsigned short*)(U + 16777216);
  float*          ybuf = (float*)d_out;

  // 1. prep: LN1 + weight convT + kv bias + pad mask
  prep_kernel<<<11932, 256, 0, stream>>>(visual, g1, b1, xbuf,
                                         Wq, Wk, Wv, Wo, W1, W2,
                                         WqT, WkT, WvT, WoT, W1T, W2T,
                                         bk, bv, bkv, text, padb);
  // 2. q-proj + kv GEMM merged
  qkv_kernel<<<592, 256, 0, stream>>>(xbuf, WqT, bq, qbuf,
                                      text, WkT, bkv, kbuf, vbuf);
  // 3. attention v3: qbuf -> qbuf in place
  attn_kernel<<<dim3(64, NH_, NB), 256, 0, stream>>>(qbuf, kbuf, vbuf, padb, lsc);
  // 4. fused o-proj + residual + LN2: y bf16 (xbuf) + y fp32 (d_out)
  gemm_oln<<<256, 256, 0, stream>>>(qbuf, WoT, bo, xbuf, alp, g2, b2,
                                    xbuf, ybuf);
  // 5. fused FFN (reads y bf16 + y fp32 resid, writes d_out fp32 in place)
  ffn_fused<<<256, 256, 0, stream>>>(xbuf, W1T, bf1, W2T, bff2, ybuf);
}